// Round 9
// baseline (137.527 us; speedup 1.0000x reference)
//
#include <hip/hip_runtime.h>
#include <math.h>

// Problem constants (from setup_inputs)
constexpr int Lc   = 4096;
constexpr int Bc   = 2;
constexpr int KNB  = 30;    // TOP_K
constexpr int NF   = 167;   // 16 pos + 144 rbf + 7 orient
constexpr int NC   = 128;   // output channels
constexpr int KP   = 200;   // padded K stride (bf16 elems) -> 400B row stride
constexpr int NKT  = 6;     // K-tiles of 32 (192 >= 167)
constexpr int CAP  = 512;   // fallback candidate capacity

typedef __attribute__((ext_vector_type(8))) short bf16x8;
typedef __attribute__((ext_vector_type(4))) float f32x4;

struct V3 { float x, y, z; };

__device__ __forceinline__ float sgnf(float v) {
    return (v > 0.f) ? 1.f : ((v < 0.f) ? -1.f : 0.f);
}
__device__ __forceinline__ unsigned long long umin64(unsigned long long a, unsigned long long b) {
    return a < b ? a : b;
}
__device__ __forceinline__ void splitbf(float v, unsigned short& h, unsigned short& l) {
    unsigned u = __float_as_uint(v);
    h = (unsigned short)(u >> 16);
    float fh = __uint_as_float((unsigned)h << 16);
    l = (unsigned short)(__float_as_uint(v - fh) >> 16);
}
__device__ __forceinline__ unsigned short bf16rne(float v) {
    unsigned u = __float_as_uint(v);
    return (unsigned short)((u + 0x7FFFu + ((u >> 16) & 1u)) >> 16);
}

// ---------------------------------------------------------------------------
// Kernel 0: pack edge_W (167x128 f32) into MFMA-fragment-ordered bf16 hi/lo.
// ---------------------------------------------------------------------------
__global__ void pack_kernel(const float* __restrict__ W,
                            unsigned short* __restrict__ Wh,
                            unsigned short* __restrict__ Wl) {
    int t = blockIdx.x * blockDim.x + threadIdx.x;
    if (t >= NKT * 8 * 64) return;
    int lane = t & 63, nt = (t >> 6) & 7, kt = t >> 9;
    int n = nt * 16 + (lane & 15);
    int kbase = kt * 32 + (lane >> 4) * 8;
    __align__(16) unsigned short h[8], l[8];
#pragma unroll
    for (int j = 0; j < 8; ++j) {
        int k = kbase + j;
        float v = (k < NF) ? W[(size_t)k * NC + n] : 0.f;
        splitbf(v, h[j], l[j]);
    }
    size_t o = (size_t)t * 8;
    *(bf16x8*)(Wh + o) = *(const bf16x8*)h;
    *(bf16x8*)(Wl + o) = *(const bf16x8*)l;
}

// ---------------------------------------------------------------------------
// Kernel 1: per-node orientation frame O (must complete before fused kernel
// since edges read arbitrary neighbors' frames).
// ---------------------------------------------------------------------------
__device__ __forceinline__ V3 unit_seg(float dx, float dy, float dz) {
    float n = sqrtf(dx * dx + dy * dy + dz * dz);
    float m = (n > 3.6f && n < 4.0f) ? 1.f : 0.f;
    float nn = fmaxf(m * n, 1e-12f);
    V3 r; r.x = dx * m / nn; r.y = dy * m / nn; r.z = dz * m / nn;
    return r;
}

__global__ void orient_kernel(const float* __restrict__ Ca, float* __restrict__ O) {
    int idx = blockIdx.x * blockDim.x + threadIdx.x;
    if (idx >= Bc * Lc) return;
    int b = idx >> 12, l = idx & (Lc - 1);
    float* o = O + (size_t)idx * 9;
    if (l < 1 || l >= Lc - 2) {
#pragma unroll
        for (int q = 0; q < 9; ++q) o[q] = 0.f;
        return;
    }
    const float* C = Ca + ((size_t)b * Lc + (l - 1)) * 3;
    float ax = C[0], ay = C[1], az = C[2];
    float bx = C[3], by = C[4], bz = C[5];
    float cx = C[6], cy = C[7], cz = C[8];
    V3 u2 = unit_seg(bx - ax, by - ay, bz - az);
    V3 u1 = unit_seg(cx - bx, cy - by, cz - bz);
    float nx = u2.y * u1.z - u2.z * u1.y;
    float ny = u2.z * u1.x - u2.x * u1.z;
    float nz = u2.x * u1.y - u2.y * u1.x;
    float nn = fmaxf(sqrtf(nx * nx + ny * ny + nz * nz), 1e-12f);
    nx /= nn; ny /= nn; nz /= nn;
    float ox = u2.x - u1.x, oy = u2.y - u1.y, oz = u2.z - u1.z;
    float on = fmaxf(sqrtf(ox * ox + oy * oy + oz * oz), 1e-12f);
    ox /= on; oy /= on; oz /= on;
    float rx = oy * nz - oz * ny;
    float ry = oz * nx - ox * nz;
    float rz = ox * ny - oy * nx;
    o[0] = ox; o[1] = oy; o[2] = oz;
    o[3] = nx; o[4] = ny; o[5] = nz;
    o[6] = rx; o[7] = ry; o[8] = rz;
}

// ---------------------------------------------------------------------------
// Kernel 2 (FUSED): top-30 select + per-edge features + split-bf16 MFMA +
// in-register LayerNorm. One 256-thread block per (b,i) row. Neighbor idx
// and distances never leave LDS.
// ---------------------------------------------------------------------------
__global__ __launch_bounds__(256) void fused_kernel(
    const float* __restrict__ Ca, const float* __restrict__ mask,
    const int* __restrict__ ridx, const int* __restrict__ clab,
    const float* __restrict__ pos_W, const float* __restrict__ pos_b,
    const unsigned short* __restrict__ Wh, const unsigned short* __restrict__ Wl,
    const float* __restrict__ ln_g, const float* __restrict__ ln_b,
    const float* __restrict__ Omat,
    float* __restrict__ outE, float* __restrict__ EidxF) {
    const int row = blockIdx.x;                 // b*L + i
    const int b = row >> 12, i = row & (Lc - 1);
    const int tid = threadIdx.x, lane = tid & 63, w = tid >> 6;

    __shared__ __align__(16) unsigned short Fh[32][KP];   // 12.8 KB
    __shared__ unsigned long long cand[CAP];              // 4 KB
    __shared__ float redf[4];
    __shared__ int redi[2][4];
    __shared__ int candN;
    __shared__ float Ssum[32][4];
    __shared__ float Ssq[32][4];
    __shared__ float2 Mstat[32];
    __shared__ int Ej[32];
    __shared__ float DnS[32];

    const float* CaB = Ca + (size_t)b * Lc * 3;
    const float* mB  = mask + (size_t)b * Lc;
    if (tid == 0) candN = 0;

    // --- Fh padding zero-fill (cols 167..199 all rows; rows 30,31) ---
    for (int q = tid; q < 32 * 33; q += 256) {
        int r = q / 33, c = 167 + q % 33;
        Fh[r][c] = 0;
    }
    for (int q = tid; q < 2 * 167; q += 256) {
        int r = 30 + q / 167, c = q % 167;
        Fh[r][c] = 0;
    }

    // ===================== Phase 1: top-30 select =====================
    const float xi = CaB[i * 3 + 0], yi = CaB[i * 3 + 1], zi = CaB[i * 3 + 2];
    const float mi = mB[i];

    float dm[16], m2a[16];
    float lmax = -1e30f;
#pragma unroll
    for (int k = 0; k < 16; ++k) {
        int j = tid + k * 256;
        float dx = CaB[j * 3 + 0] - xi;
        float dy = CaB[j * 3 + 1] - yi;
        float dz = CaB[j * 3 + 2] - zi;
        float d = sqrtf(dx * dx + dy * dy + dz * dz + 1e-6f);
        float m2 = mi * mB[j];
        float v = m2 * d;
        dm[k] = v; m2a[k] = m2;
        lmax = fmaxf(lmax, v);
    }
    for (int off = 32; off; off >>= 1) lmax = fmaxf(lmax, __shfl_xor(lmax, off));
    if (lane == 0) redf[w] = lmax;
    __syncthreads();
    const float dmax = fmaxf(fmaxf(redf[0], redf[1]), fmaxf(redf[2], redf[3]));

#pragma unroll
    for (int k = 0; k < 16; ++k) dm[k] = dm[k] + (1.f - m2a[k]) * dmax;

    float T = dmax * 0.19435f;     // (30/4096)^(1/3)
    int c = 0;
    for (int iter = 0; iter < 32; ++iter) {
        int lc = 0;
#pragma unroll
        for (int k = 0; k < 16; ++k) lc += (dm[k] <= T) ? 1 : 0;
        for (int off = 32; off; off >>= 1) lc += __shfl_xor(lc, off);
        if (lane == 0) redi[iter & 1][w] = lc;
        __syncthreads();
        c = redi[iter & 1][0] + redi[iter & 1][1] + redi[iter & 1][2] + redi[iter & 1][3];
        if (c >= KNB && c <= 64) break;
        if (iter >= 12 && c >= KNB && c <= CAP) break;
        if (c < KNB)
            T *= (c == 0) ? 1.7f
                          : fminf(1.7f, 1.05f * cbrtf((float)(KNB + 15) / (float)c));
        else
            T *= fmaxf(0.55f, 1.05f * cbrtf(45.f / (float)c));
    }

#pragma unroll
    for (int k = 0; k < 16; ++k) {
        if (dm[k] <= T) {
            int idx = atomicAdd(&candN, 1);
            if (idx < CAP)
                cand[idx] = ((unsigned long long)__float_as_uint(dm[k]) << 32) |
                            (unsigned)(tid + k * 256);
        }
    }
    __syncthreads();

    if (w == 0) {
        int C = candN; if (C > CAP) C = CAP;
        if (C <= 64) {
            unsigned long long key = (lane < C) ? cand[lane] : ~0ULL;
#pragma unroll
            for (int size = 2; size <= 64; size <<= 1) {
#pragma unroll
                for (int stride = size >> 1; stride; stride >>= 1) {
                    unsigned long long other = __shfl_xor(key, stride);
                    bool dirUp = ((lane & size) == 0);
                    bool takeMin = ((lane & stride) == 0) ? dirUp : !dirUp;
                    bool less = other < key;
                    unsigned long long mn = less ? other : key;
                    unsigned long long mx = less ? key : other;
                    key = takeMin ? mn : mx;
                }
            }
            if (lane < KNB) {
                int jw = (int)(key & 0xFFFFFFFFULL);
                EidxF[(size_t)row * KNB + lane] = (float)jw;
                Ej[lane] = jw;
                DnS[lane] = __uint_as_float((unsigned)(key >> 32));
            }
        } else {
            unsigned long long r[CAP / 64];
#pragma unroll
            for (int q = 0; q < CAP / 64; ++q) {
                int idx = lane + q * 64;
                r[q] = (idx < C) ? cand[idx] : ~0ULL;
            }
            for (int p = 0; p < KNB; ++p) {
                unsigned long long mn = r[0];
#pragma unroll
                for (int q = 1; q < CAP / 64; ++q) mn = umin64(mn, r[q]);
                for (int off = 32; off; off >>= 1) mn = umin64(mn, __shfl_xor(mn, off));
                if (lane == 0) {
                    int jw = (int)(mn & 0xFFFFFFFFULL);
                    EidxF[(size_t)row * KNB + p] = (float)jw;
                    Ej[p] = jw;
                    DnS[p] = __uint_as_float((unsigned)(mn >> 32));
                }
#pragma unroll
                for (int q = 0; q < CAP / 64; ++q) if (r[q] == mn) r[q] = ~0ULL;
            }
        }
    }
    __syncthreads();

    // ===================== Phase 2: features =====================
    auto putF = [&](int e, int k, float v) { Fh[e][k] = bf16rne(v); };
    auto loadC = [&](int n) {
        V3 r;
        if (n >= 0 && n < Lc) { r.x = CaB[n*3]; r.y = CaB[n*3+1]; r.z = CaB[n*3+2]; }
        else { r.x = 0.f; r.y = 0.f; r.z = 0.f; }
        return r;
    };
    const int pa_t[10] = {0,0,0,2,0,0,1,1,2,2};
    const int pb_t[10] = {0,0,0,2,1,2,0,2,0,1};

    for (int task = tid; task < 330; task += 256) {
        int e = task % 30;
        int g = task / 30;
        int j = Ej[e];
        if (g == 0) {
            int off = ridx[(size_t)b * Lc + i] - ridx[(size_t)b * Lc + j];
            int ec = (clab[(size_t)b * Lc + i] == clab[(size_t)b * Lc + j]) ? 1 : 0;
            int d = ec ? min(max(off + 32, 0), 64) : 65;
#pragma unroll
            for (int cc = 0; cc < 16; ++cc) putF(e, cc, pos_W[d * 16 + cc] + pos_b[cc]);
        } else if (g < 10) {
            float D;
            if (g == 1) {
                D = DnS[e];
            } else {
                V3 A = loadC(i - 1 + pa_t[g]);
                V3 B = loadC(j - 1 + pb_t[g]);
                float dx = A.x - B.x, dy = A.y - B.y, dz = A.z - B.z;
                D = sqrtf(dx * dx + dy * dy + dz * dz + 1e-6f);
            }
            int k0 = 16 * g;
#pragma unroll
            for (int m = 0; m < 16; ++m) {
                float mu = 2.f + (20.f / 15.f) * (float)m;
                float z = (D - mu) * (1.f / 1.25f);
                putF(e, k0 + m, __expf(-z * z));
            }
        } else {
            const float* Om = Omat + (size_t)row * 9;
            const float* On = Omat + ((size_t)b * Lc + j) * 9;
            V3 Ai = loadC(i), Bj = loadC(j);
            float dvx = Bj.x - Ai.x, dvy = Bj.y - Ai.y, dvz = Bj.z - Ai.z;
            float u0 = Om[0] * dvx + Om[1] * dvy + Om[2] * dvz;
            float u1 = Om[3] * dvx + Om[4] * dvy + Om[5] * dvz;
            float u2 = Om[6] * dvx + Om[7] * dvy + Om[8] * dvz;
            float un = fmaxf(sqrtf(u0 * u0 + u1 * u1 + u2 * u2), 1e-12f);
            putF(e, 160, u0 / un); putF(e, 161, u1 / un); putF(e, 162, u2 / un);
            float R[3][3];
#pragma unroll
            for (int a = 0; a < 3; ++a)
#pragma unroll
                for (int m = 0; m < 3; ++m)
                    R[a][m] = Om[0 * 3 + a] * On[0 * 3 + m] +
                              Om[1 * 3 + a] * On[1 * 3 + m] +
                              Om[2 * 3 + a] * On[2 * 3 + m];
            float Rxx = R[0][0], Ryy = R[1][1], Rzz = R[2][2];
            float m0 = 0.5f * sqrtf(fabsf(1.f + Rxx - Ryy - Rzz));
            float m1 = 0.5f * sqrtf(fabsf(1.f - Rxx + Ryy - Rzz));
            float m2 = 0.5f * sqrtf(fabsf(1.f - Rxx - Ryy + Rzz));
            float qx = sgnf(R[2][1] - R[1][2]) * m0;
            float qy = sgnf(R[0][2] - R[2][0]) * m1;
            float qz = sgnf(R[1][0] - R[0][1]) * m2;
            float qw = sqrtf(fmaxf(0.f, 1.f + Rxx + Ryy + Rzz)) * 0.5f;
            float qn = fmaxf(sqrtf(qx * qx + qy * qy + qz * qz + qw * qw), 1e-12f);
            putF(e, 163, qx / qn); putF(e, 164, qy / qn);
            putF(e, 165, qz / qn); putF(e, 166, qw / qn);
        }
    }
    __syncthreads();

    // ===================== Phase 3: MFMA + LN =====================
    const int arow = lane & 15, agrp = lane >> 4;
    const int ng0 = w * 2;
    f32x4 acc[2][2];
#pragma unroll
    for (int m = 0; m < 2; ++m)
#pragma unroll
        for (int n = 0; n < 2; ++n) acc[m][n] = (f32x4){0.f, 0.f, 0.f, 0.f};

    const bf16x8* WhF = (const bf16x8*)Wh;
    const bf16x8* WlF = (const bf16x8*)Wl;

#pragma unroll
    for (int kt = 0; kt < NKT; ++kt) {
        const int kof = kt * 32 + agrp * 8;
        bf16x8 a0 = *(const bf16x8*)&Fh[arow][kof];
        bf16x8 a1 = *(const bf16x8*)&Fh[16 + arow][kof];
        bf16x8 b0h = WhF[(kt * 8 + ng0) * 64 + lane];
        bf16x8 b1h = WhF[(kt * 8 + ng0 + 1) * 64 + lane];
        bf16x8 b0l = WlF[(kt * 8 + ng0) * 64 + lane];
        bf16x8 b1l = WlF[(kt * 8 + ng0 + 1) * 64 + lane];

        acc[0][0] = __builtin_amdgcn_mfma_f32_16x16x32_bf16(a0, b0h, acc[0][0], 0, 0, 0);
        acc[0][0] = __builtin_amdgcn_mfma_f32_16x16x32_bf16(a0, b0l, acc[0][0], 0, 0, 0);
        acc[0][1] = __builtin_amdgcn_mfma_f32_16x16x32_bf16(a0, b1h, acc[0][1], 0, 0, 0);
        acc[0][1] = __builtin_amdgcn_mfma_f32_16x16x32_bf16(a0, b1l, acc[0][1], 0, 0, 0);
        acc[1][0] = __builtin_amdgcn_mfma_f32_16x16x32_bf16(a1, b0h, acc[1][0], 0, 0, 0);
        acc[1][0] = __builtin_amdgcn_mfma_f32_16x16x32_bf16(a1, b0l, acc[1][0], 0, 0, 0);
        acc[1][1] = __builtin_amdgcn_mfma_f32_16x16x32_bf16(a1, b1h, acc[1][1], 0, 0, 0);
        acc[1][1] = __builtin_amdgcn_mfma_f32_16x16x32_bf16(a1, b1l, acc[1][1], 0, 0, 0);
    }

    float ps[2][4], pq[2][4];
#pragma unroll
    for (int m = 0; m < 2; ++m)
#pragma unroll
        for (int r = 0; r < 4; ++r) {
            float v0 = acc[m][0][r], v1 = acc[m][1][r];
            ps[m][r] = v0 + v1;
            pq[m][r] = v0 * v0 + v1 * v1;
        }
#pragma unroll
    for (int off = 1; off < 16; off <<= 1) {
#pragma unroll
        for (int m = 0; m < 2; ++m)
#pragma unroll
            for (int r = 0; r < 4; ++r) {
                ps[m][r] += __shfl_xor(ps[m][r], off);
                pq[m][r] += __shfl_xor(pq[m][r], off);
            }
    }
    if (arow == 0) {
#pragma unroll
        for (int m = 0; m < 2; ++m)
#pragma unroll
            for (int r = 0; r < 4; ++r) {
                int me = m * 16 + agrp * 4 + r;
                Ssum[me][w] = ps[m][r];
                Ssq[me][w] = pq[m][r];
            }
    }
    __syncthreads();
    if (tid < 32) {
        float s = Ssum[tid][0] + Ssum[tid][1] + Ssum[tid][2] + Ssum[tid][3];
        float q = Ssq[tid][0] + Ssq[tid][1] + Ssq[tid][2] + Ssq[tid][3];
        float mean = s * (1.f / 128.f);
        float var = q * (1.f / 128.f) - mean * mean;
        Mstat[tid] = make_float2(mean, 1.f / sqrtf(var + 1e-5f));
    }
    __syncthreads();

    float gg[2], bb[2];
#pragma unroll
    for (int n = 0; n < 2; ++n) {
        int ce = (ng0 + n) * 16 + arow;
        gg[n] = ln_g[ce];
        bb[n] = ln_b[ce];
    }
#pragma unroll
    for (int m = 0; m < 2; ++m)
#pragma unroll
        for (int r = 0; r < 4; ++r) {
            int me = m * 16 + agrp * 4 + r;
            if (me >= KNB) continue;
            float2 st = Mstat[me];
            size_t base = ((size_t)row * KNB + me) * NC;
#pragma unroll
            for (int n = 0; n < 2; ++n) {
                int ce = (ng0 + n) * 16 + arow;
                outE[base + ce] = (acc[m][n][r] - st.x) * st.y * gg[n] + bb[n];
            }
        }
}

// ---------------------------------------------------------------------------
extern "C" void kernel_launch(void* const* d_in, const int* in_sizes, int n_in,
                              void* d_out, int out_size, void* d_ws, size_t ws_size,
                              hipStream_t stream) {
    const float* Ca     = (const float*)d_in[0];
    const float* mask   = (const float*)d_in[1];
    const int*   ridx   = (const int*)d_in[2];
    const int*   clab   = (const int*)d_in[3];
    const float* pos_W  = (const float*)d_in[4];
    const float* pos_b  = (const float*)d_in[5];
    const float* edge_W = (const float*)d_in[6];
    const float* ln_g   = (const float*)d_in[7];
    const float* ln_b   = (const float*)d_in[8];

    float* outE  = (float*)d_out;
    float* EidxF = outE + (size_t)Bc * Lc * KNB * NC;   // output 1 (as float values)

    float* Omat  = (float*)d_ws;                           // B*L*9 f32
    unsigned short* Wh = (unsigned short*)(Omat + (size_t)Bc * Lc * 9);
    unsigned short* Wl = Wh + (size_t)NKT * 8 * 64 * 8;    // 24576 each

    const int rows = Bc * Lc;
    pack_kernel<<<12, 256, 0, stream>>>(edge_W, Wh, Wl);
    orient_kernel<<<(rows + 255) / 256, 256, 0, stream>>>(Ca, Omat);
    fused_kernel<<<rows, 256, 0, stream>>>(Ca, mask, ridx, clab, pos_W, pos_b,
                                           Wh, Wl, ln_g, ln_b, Omat, outE, EidxF);
}

// Round 10
// 128.589 us; speedup vs baseline: 1.0695x; 1.0695x over previous
//
#include <hip/hip_runtime.h>
#include <math.h>

// Problem constants (from setup_inputs)
constexpr int Lc   = 4096;
constexpr int Bc   = 2;
constexpr int KNB  = 30;    // TOP_K
constexpr int NF   = 167;   // 16 pos + 144 rbf + 7 orient
constexpr int NC   = 128;   // output channels
constexpr int KP   = 200;   // padded K stride (bf16 elems) -> 400B row stride
constexpr int NKT  = 6;     // K-tiles of 32 (192 >= 167)
constexpr int CAP  = 512;   // fallback candidate capacity

typedef __attribute__((ext_vector_type(8))) short bf16x8;
typedef __attribute__((ext_vector_type(4))) float f32x4;

struct V3 { float x, y, z; };

__device__ __forceinline__ float sgnf(float v) {
    return (v > 0.f) ? 1.f : ((v < 0.f) ? -1.f : 0.f);
}
__device__ __forceinline__ unsigned long long umin64(unsigned long long a, unsigned long long b) {
    return a < b ? a : b;
}
__device__ __forceinline__ void splitbf(float v, unsigned short& h, unsigned short& l) {
    unsigned u = __float_as_uint(v);
    h = (unsigned short)(u >> 16);
    float fh = __uint_as_float((unsigned)h << 16);
    l = (unsigned short)(__float_as_uint(v - fh) >> 16);
}
__device__ __forceinline__ unsigned short bf16rne(float v) {
    unsigned u = __float_as_uint(v);
    return (unsigned short)((u + 0x7FFFu + ((u >> 16) & 1u)) >> 16);
}

// ---------------------------------------------------------------------------
// Kernel 0: pack edge_W (167x128 f32) into MFMA-fragment-ordered bf16 hi/lo.
// ---------------------------------------------------------------------------
__global__ void pack_kernel(const float* __restrict__ W,
                            unsigned short* __restrict__ Wh,
                            unsigned short* __restrict__ Wl) {
    int t = blockIdx.x * blockDim.x + threadIdx.x;
    if (t >= NKT * 8 * 64) return;
    int lane = t & 63, nt = (t >> 6) & 7, kt = t >> 9;
    int n = nt * 16 + (lane & 15);
    int kbase = kt * 32 + (lane >> 4) * 8;
    __align__(16) unsigned short h[8], l[8];
#pragma unroll
    for (int j = 0; j < 8; ++j) {
        int k = kbase + j;
        float v = (k < NF) ? W[(size_t)k * NC + n] : 0.f;
        splitbf(v, h[j], l[j]);
    }
    size_t o = (size_t)t * 8;
    *(bf16x8*)(Wh + o) = *(const bf16x8*)h;
    *(bf16x8*)(Wl + o) = *(const bf16x8*)l;
}

// ---------------------------------------------------------------------------
// Kernel 1 (v5): masked distance + top-30 in SQUARED-distance space.
// d = sqrt(ss+1e-6) is strictly monotone in ss, so (ss_bits<<32|j) ordering
// == (d_bits<<32|j) ordering incl. JAX tie semantics. Exact d reconstructed
// only for the 30 winners. Threshold loop on Tss (squared factors).
// ---------------------------------------------------------------------------
__global__ __launch_bounds__(256) void topk_kernel(
    const float* __restrict__ Ca, const float* __restrict__ mask,
    float* __restrict__ Dn, float* __restrict__ EidxF, int* __restrict__ EidxI) {
    const int row = blockIdx.x;                 // b*L + i
    const int b = row >> 12, i = row & (Lc - 1);
    const float* CaB = Ca + (size_t)b * Lc * 3;
    const float* mB  = mask + (size_t)b * Lc;
    const float xi = CaB[i * 3 + 0], yi = CaB[i * 3 + 1], zi = CaB[i * 3 + 2];
    const float mi = mB[i];

    __shared__ unsigned long long cand[CAP];         // 4 KB
    __shared__ float redf[4];
    __shared__ int redi[2][4];
    __shared__ int candN;

    const int t = threadIdx.x, lane = t & 63, wid = t >> 6;
    if (t == 0) candN = 0;

    // squared distances in registers, strided for coalescing
    float ss[16], m2a[16];
    float lmax = -1e30f;
#pragma unroll
    for (int k = 0; k < 16; ++k) {
        int j = t + k * 256;
        float dx = CaB[j * 3 + 0] - xi;
        float dy = CaB[j * 3 + 1] - yi;
        float dz = CaB[j * 3 + 2] - zi;
        float s = dx * dx + dy * dy + dz * dz;
        float m2 = mi * mB[j];
        float v = m2 * s;
        ss[k] = v; m2a[k] = m2;
        lmax = fmaxf(lmax, v);
    }
    for (int off = 32; off; off >>= 1) lmax = fmaxf(lmax, __shfl_xor(lmax, off));
    if (lane == 0) redf[wid] = lmax;
    __syncthreads();
    const float ssmax = fmaxf(fmaxf(redf[0], redf[1]), fmaxf(redf[2], redf[3]));

    // adjust (identity for mask==1): masked-out entries pushed to row max
#pragma unroll
    for (int k = 0; k < 16; ++k) ss[k] = ss[k] + (1.f - m2a[k]) * ssmax;

    // --- threshold search in ss-space: prefer c in [KNB,64]; accept CAP late ---
    float T = ssmax * 0.037772f;   // (30/4096)^(2/3)
    int c = 0;
    for (int iter = 0; iter < 32; ++iter) {
        int lc = 0;
#pragma unroll
        for (int k = 0; k < 16; ++k) lc += (ss[k] <= T) ? 1 : 0;
        for (int off = 32; off; off >>= 1) lc += __shfl_xor(lc, off);
        if (lane == 0) redi[iter & 1][wid] = lc;
        __syncthreads();
        c = redi[iter & 1][0] + redi[iter & 1][1] + redi[iter & 1][2] + redi[iter & 1][3];
        if (c >= KNB && c <= 64) break;
        if (iter >= 12 && c >= KNB && c <= CAP) break;
        if (c < KNB) {
            if (c == 0) T *= 2.89f;
            else {
                float f = cbrtf((float)(KNB + 15) / (float)c);
                T *= fminf(2.89f, 1.1025f * f * f);
            }
        } else {
            float f = cbrtf(45.f / (float)c);
            T *= fmaxf(0.3025f, 1.1025f * f * f);
        }
    }

    // collect candidates (<= T)
#pragma unroll
    for (int k = 0; k < 16; ++k) {
        if (ss[k] <= T) {
            int idx = atomicAdd(&candN, 1);
            if (idx < CAP)
                cand[idx] = ((unsigned long long)__float_as_uint(ss[k]) << 32) |
                            (unsigned)(t + k * 256);
        }
    }
    __syncthreads();

    if (wid == 0) {
        int C = candN; if (C > CAP) C = CAP;
        if (C <= 64) {
            unsigned long long key = (lane < C) ? cand[lane] : ~0ULL;
#pragma unroll
            for (int size = 2; size <= 64; size <<= 1) {
#pragma unroll
                for (int stride = size >> 1; stride; stride >>= 1) {
                    unsigned long long other = __shfl_xor(key, stride);
                    bool dirUp = ((lane & size) == 0);
                    bool takeMin = ((lane & stride) == 0) ? dirUp : !dirUp;
                    bool less = other < key;
                    unsigned long long mn = less ? other : key;
                    unsigned long long mx = less ? key : other;
                    key = takeMin ? mn : mx;
                }
            }
            if (lane < KNB) {
                int jw = (int)(key & 0xFFFFFFFFULL);
                float sv = __uint_as_float((unsigned)(key >> 32));
                EidxF[(size_t)row * KNB + lane] = (float)jw;
                EidxI[(size_t)row * KNB + lane] = jw;
                Dn[(size_t)row * KNB + lane] = sqrtf(sv + 1e-6f);
            }
        } else {
            unsigned long long r[CAP / 64];
#pragma unroll
            for (int q = 0; q < CAP / 64; ++q) {
                int idx = lane + q * 64;
                r[q] = (idx < C) ? cand[idx] : ~0ULL;
            }
            for (int p = 0; p < KNB; ++p) {
                unsigned long long mn = r[0];
#pragma unroll
                for (int q = 1; q < CAP / 64; ++q) mn = umin64(mn, r[q]);
                for (int off = 32; off; off >>= 1) mn = umin64(mn, __shfl_xor(mn, off));
                if (lane == 0) {
                    int jw = (int)(mn & 0xFFFFFFFFULL);
                    float sv = __uint_as_float((unsigned)(mn >> 32));
                    EidxF[(size_t)row * KNB + p] = (float)jw;
                    EidxI[(size_t)row * KNB + p] = jw;
                    Dn[(size_t)row * KNB + p] = sqrtf(sv + 1e-6f);
                }
#pragma unroll
                for (int q = 0; q < CAP / 64; ++q) if (r[q] == mn) r[q] = ~0ULL;
            }
        }
    }
}

// ---------------------------------------------------------------------------
// Kernel 2: per-node orientation frame O (unchanged).
// ---------------------------------------------------------------------------
__device__ __forceinline__ V3 unit_seg(float dx, float dy, float dz) {
    float n = sqrtf(dx * dx + dy * dy + dz * dz);
    float m = (n > 3.6f && n < 4.0f) ? 1.f : 0.f;
    float nn = fmaxf(m * n, 1e-12f);
    V3 r; r.x = dx * m / nn; r.y = dy * m / nn; r.z = dz * m / nn;
    return r;
}

__global__ void orient_kernel(const float* __restrict__ Ca, float* __restrict__ O) {
    int idx = blockIdx.x * blockDim.x + threadIdx.x;
    if (idx >= Bc * Lc) return;
    int b = idx >> 12, l = idx & (Lc - 1);
    float* o = O + (size_t)idx * 9;
    if (l < 1 || l >= Lc - 2) {
#pragma unroll
        for (int q = 0; q < 9; ++q) o[q] = 0.f;
        return;
    }
    const float* C = Ca + ((size_t)b * Lc + (l - 1)) * 3;
    float ax = C[0], ay = C[1], az = C[2];
    float bx = C[3], by = C[4], bz = C[5];
    float cx = C[6], cy = C[7], cz = C[8];
    V3 u2 = unit_seg(bx - ax, by - ay, bz - az);
    V3 u1 = unit_seg(cx - bx, cy - by, cz - bz);
    float nx = u2.y * u1.z - u2.z * u1.y;
    float ny = u2.z * u1.x - u2.x * u1.z;
    float nz = u2.x * u1.y - u2.y * u1.x;
    float nn = fmaxf(sqrtf(nx * nx + ny * ny + nz * nz), 1e-12f);
    nx /= nn; ny /= nn; nz /= nn;
    float ox = u2.x - u1.x, oy = u2.y - u1.y, oz = u2.z - u1.z;
    float on = fmaxf(sqrtf(ox * ox + oy * oy + oz * oz), 1e-12f);
    ox /= on; oy /= on; oz /= on;
    float rx = oy * nz - oz * ny;
    float ry = oz * nx - ox * nz;
    float rz = ox * ny - oy * nx;
    o[0] = ox; o[1] = oy; o[2] = oz;
    o[3] = nx; o[4] = ny; o[5] = nz;
    o[6] = rx; o[7] = ry; o[8] = rz;
}

// ---------------------------------------------------------------------------
// Kernel 3 (v4): fused features (bf16, PAIRED u32 LDS writes) + MFMA
// (a * (Wh + Wl), 8 MFMA/kt) + in-register LayerNorm.
// ---------------------------------------------------------------------------
__global__ __launch_bounds__(256) void edge_kernel(
    const float* __restrict__ Ca, const int* __restrict__ ridx,
    const int* __restrict__ clab, const float* __restrict__ pos_W,
    const float* __restrict__ pos_b,
    const unsigned short* __restrict__ Wh, const unsigned short* __restrict__ Wl,
    const float* __restrict__ ln_g, const float* __restrict__ ln_b,
    const float* __restrict__ Dn, const int* __restrict__ EidxI,
    const float* __restrict__ Omat, float* __restrict__ outE) {
    const int row = blockIdx.x;                 // b*L + i
    const int b = row >> 12, i = row & (Lc - 1);
    const int tid = threadIdx.x, lane = tid & 63, w = tid >> 6;

    __shared__ __align__(16) unsigned short Fh[32][KP];   // 12.5 KB
    __shared__ float Ssum[32][4];
    __shared__ float Ssq[32][4];
    __shared__ float2 Mstat[32];
    __shared__ int Ej[32];

    const float* CaB = Ca + (size_t)b * Lc * 3;

    // --- targeted zero-fill: padding cols 167..199 all rows; rows 30,31 ---
    for (int q = tid; q < 32 * 33; q += 256) {
        int r = q / 33, c = 167 + q % 33;
        Fh[r][c] = 0;
    }
    for (int q = tid; q < 2 * 167; q += 256) {
        int r = 30 + q / 167, c = q % 167;
        Fh[r][c] = 0;
    }
    if (tid < KNB) Ej[tid] = EidxI[(size_t)row * KNB + tid];
    __syncthreads();

    // --- feature build: 330 tasks over 256 threads, paired u32 writes ---
    auto putF2 = [&](int e, int k, float va, float vb) {   // k even
        unsigned pv = (unsigned)bf16rne(va) | ((unsigned)bf16rne(vb) << 16);
        *(unsigned*)&Fh[e][k] = pv;
    };
    auto loadC = [&](int n) {
        V3 r;
        if (n >= 0 && n < Lc) { r.x = CaB[n*3]; r.y = CaB[n*3+1]; r.z = CaB[n*3+2]; }
        else { r.x = 0.f; r.y = 0.f; r.z = 0.f; }
        return r;
    };
    const int pa_t[10] = {0,0,0,2,0,0,1,1,2,2};
    const int pb_t[10] = {0,0,0,2,1,2,0,2,0,1};

    for (int task = tid; task < 330; task += 256) {
        int e = task % 30;
        int g = task / 30;
        int j = Ej[e];
        if (g == 0) {
            int off = ridx[(size_t)b * Lc + i] - ridx[(size_t)b * Lc + j];
            int ec = (clab[(size_t)b * Lc + i] == clab[(size_t)b * Lc + j]) ? 1 : 0;
            int d = ec ? min(max(off + 32, 0), 64) : 65;
#pragma unroll
            for (int cc = 0; cc < 16; cc += 2)
                putF2(e, cc, pos_W[d * 16 + cc] + pos_b[cc],
                             pos_W[d * 16 + cc + 1] + pos_b[cc + 1]);
        } else if (g < 10) {
            float D;
            if (g == 1) {
                D = Dn[(size_t)row * KNB + e];
            } else {
                V3 A = loadC(i - 1 + pa_t[g]);
                V3 B = loadC(j - 1 + pb_t[g]);
                float dx = A.x - B.x, dy = A.y - B.y, dz = A.z - B.z;
                D = sqrtf(dx * dx + dy * dy + dz * dz + 1e-6f);
            }
            int k0 = 16 * g;
#pragma unroll
            for (int m = 0; m < 16; m += 2) {
                float mu0 = 2.f + (20.f / 15.f) * (float)m;
                float mu1 = 2.f + (20.f / 15.f) * (float)(m + 1);
                float z0 = (D - mu0) * (1.f / 1.25f);
                float z1 = (D - mu1) * (1.f / 1.25f);
                putF2(e, k0 + m, __expf(-z0 * z0), __expf(-z1 * z1));
            }
        } else {
            const float* Om = Omat + (size_t)row * 9;
            const float* On = Omat + ((size_t)b * Lc + j) * 9;
            V3 Ai = loadC(i), Bj = loadC(j);
            float dvx = Bj.x - Ai.x, dvy = Bj.y - Ai.y, dvz = Bj.z - Ai.z;
            float u0 = Om[0] * dvx + Om[1] * dvy + Om[2] * dvz;
            float u1 = Om[3] * dvx + Om[4] * dvy + Om[5] * dvz;
            float u2 = Om[6] * dvx + Om[7] * dvy + Om[8] * dvz;
            float un = fmaxf(sqrtf(u0 * u0 + u1 * u1 + u2 * u2), 1e-12f);
            float R[3][3];
#pragma unroll
            for (int a = 0; a < 3; ++a)
#pragma unroll
                for (int m = 0; m < 3; ++m)
                    R[a][m] = Om[0 * 3 + a] * On[0 * 3 + m] +
                              Om[1 * 3 + a] * On[1 * 3 + m] +
                              Om[2 * 3 + a] * On[2 * 3 + m];
            float Rxx = R[0][0], Ryy = R[1][1], Rzz = R[2][2];
            float m0 = 0.5f * sqrtf(fabsf(1.f + Rxx - Ryy - Rzz));
            float m1 = 0.5f * sqrtf(fabsf(1.f - Rxx + Ryy - Rzz));
            float m2 = 0.5f * sqrtf(fabsf(1.f - Rxx - Ryy + Rzz));
            float qx = sgnf(R[2][1] - R[1][2]) * m0;
            float qy = sgnf(R[0][2] - R[2][0]) * m1;
            float qz = sgnf(R[1][0] - R[0][1]) * m2;
            float qw = sqrtf(fmaxf(0.f, 1.f + Rxx + Ryy + Rzz)) * 0.5f;
            float qn = fmaxf(sqrtf(qx * qx + qy * qy + qz * qz + qw * qw), 1e-12f);
            putF2(e, 160, u0 / un, u1 / un);
            putF2(e, 162, u2 / un, qx / qn);
            putF2(e, 164, qy / qn, qz / qn);
            putF2(e, 166, qw / qn, 0.f);      // col 167 is zero padding
        }
    }
    __syncthreads();

    // --- MFMA phase: wave w owns N columns [w*32, w*32+32) ---
    const int arow = lane & 15, agrp = lane >> 4;
    const int ng0 = w * 2;
    f32x4 acc[2][2];
#pragma unroll
    for (int m = 0; m < 2; ++m)
#pragma unroll
        for (int n = 0; n < 2; ++n) acc[m][n] = (f32x4){0.f, 0.f, 0.f, 0.f};

    const bf16x8* WhF = (const bf16x8*)Wh;
    const bf16x8* WlF = (const bf16x8*)Wl;

#pragma unroll
    for (int kt = 0; kt < NKT; ++kt) {
        const int kof = kt * 32 + agrp * 8;
        bf16x8 a0 = *(const bf16x8*)&Fh[arow][kof];
        bf16x8 a1 = *(const bf16x8*)&Fh[16 + arow][kof];
        bf16x8 b0h = WhF[(kt * 8 + ng0) * 64 + lane];
        bf16x8 b1h = WhF[(kt * 8 + ng0 + 1) * 64 + lane];
        bf16x8 b0l = WlF[(kt * 8 + ng0) * 64 + lane];
        bf16x8 b1l = WlF[(kt * 8 + ng0 + 1) * 64 + lane];

        acc[0][0] = __builtin_amdgcn_mfma_f32_16x16x32_bf16(a0, b0h, acc[0][0], 0, 0, 0);
        acc[0][0] = __builtin_amdgcn_mfma_f32_16x16x32_bf16(a0, b0l, acc[0][0], 0, 0, 0);
        acc[0][1] = __builtin_amdgcn_mfma_f32_16x16x32_bf16(a0, b1h, acc[0][1], 0, 0, 0);
        acc[0][1] = __builtin_amdgcn_mfma_f32_16x16x32_bf16(a0, b1l, acc[0][1], 0, 0, 0);
        acc[1][0] = __builtin_amdgcn_mfma_f32_16x16x32_bf16(a1, b0h, acc[1][0], 0, 0, 0);
        acc[1][0] = __builtin_amdgcn_mfma_f32_16x16x32_bf16(a1, b0l, acc[1][0], 0, 0, 0);
        acc[1][1] = __builtin_amdgcn_mfma_f32_16x16x32_bf16(a1, b1h, acc[1][1], 0, 0, 0);
        acc[1][1] = __builtin_amdgcn_mfma_f32_16x16x32_bf16(a1, b1l, acc[1][1], 0, 0, 0);
    }

    // --- LN stats from accumulators ---
    float ps[2][4], pq[2][4];
#pragma unroll
    for (int m = 0; m < 2; ++m)
#pragma unroll
        for (int r = 0; r < 4; ++r) {
            float v0 = acc[m][0][r], v1 = acc[m][1][r];
            ps[m][r] = v0 + v1;
            pq[m][r] = v0 * v0 + v1 * v1;
        }
#pragma unroll
    for (int off = 1; off < 16; off <<= 1) {
#pragma unroll
        for (int m = 0; m < 2; ++m)
#pragma unroll
            for (int r = 0; r < 4; ++r) {
                ps[m][r] += __shfl_xor(ps[m][r], off);
                pq[m][r] += __shfl_xor(pq[m][r], off);
            }
    }
    if (arow == 0) {
#pragma unroll
        for (int m = 0; m < 2; ++m)
#pragma unroll
            for (int r = 0; r < 4; ++r) {
                int me = m * 16 + agrp * 4 + r;
                Ssum[me][w] = ps[m][r];
                Ssq[me][w] = pq[m][r];
            }
    }
    __syncthreads();
    if (tid < 32) {
        float s = Ssum[tid][0] + Ssum[tid][1] + Ssum[tid][2] + Ssum[tid][3];
        float q = Ssq[tid][0] + Ssq[tid][1] + Ssq[tid][2] + Ssq[tid][3];
        float mean = s * (1.f / 128.f);
        float var = q * (1.f / 128.f) - mean * mean;
        Mstat[tid] = make_float2(mean, 1.f / sqrtf(var + 1e-5f));
    }
    __syncthreads();

    float gg[2], bb[2];
#pragma unroll
    for (int n = 0; n < 2; ++n) {
        int ce = (ng0 + n) * 16 + arow;
        gg[n] = ln_g[ce];
        bb[n] = ln_b[ce];
    }
#pragma unroll
    for (int m = 0; m < 2; ++m)
#pragma unroll
        for (int r = 0; r < 4; ++r) {
            int me = m * 16 + agrp * 4 + r;
            if (me >= KNB) continue;
            float2 st = Mstat[me];
            size_t base = ((size_t)row * KNB + me) * NC;
#pragma unroll
            for (int n = 0; n < 2; ++n) {
                int ce = (ng0 + n) * 16 + arow;
                outE[base + ce] = (acc[m][n][r] - st.x) * st.y * gg[n] + bb[n];
            }
        }
}

// ---------------------------------------------------------------------------
extern "C" void kernel_launch(void* const* d_in, const int* in_sizes, int n_in,
                              void* d_out, int out_size, void* d_ws, size_t ws_size,
                              hipStream_t stream) {
    const float* Ca     = (const float*)d_in[0];
    const float* mask   = (const float*)d_in[1];
    const int*   ridx   = (const int*)d_in[2];
    const int*   clab   = (const int*)d_in[3];
    const float* pos_W  = (const float*)d_in[4];
    const float* pos_b  = (const float*)d_in[5];
    const float* edge_W = (const float*)d_in[6];
    const float* ln_g   = (const float*)d_in[7];
    const float* ln_b   = (const float*)d_in[8];

    float* outE  = (float*)d_out;
    float* EidxF = outE + (size_t)Bc * Lc * KNB * NC;   // output 1 (as float values)

    float* Dn    = (float*)d_ws;                           // B*L*30 f32
    float* Omat  = Dn + (size_t)Bc * Lc * KNB;             // B*L*9 f32
    int*   EidxI = (int*)(Omat + (size_t)Bc * Lc * 9);     // B*L*30 i32
    unsigned short* Wh = (unsigned short*)(EidxI + (size_t)Bc * Lc * KNB);
    unsigned short* Wl = Wh + (size_t)NKT * 8 * 64 * 8;    // 24576 each

    const int rows = Bc * Lc;
    pack_kernel<<<12, 256, 0, stream>>>(edge_W, Wh, Wl);
    topk_kernel<<<rows, 256, 0, stream>>>(Ca, mask, Dn, EidxF, EidxI);
    orient_kernel<<<(rows + 255) / 256, 256, 0, stream>>>(Ca, Omat);
    edge_kernel<<<rows, 256, 0, stream>>>(Ca, ridx, clab, pos_W, pos_b, Wh, Wl,
                                          ln_g, ln_b, Dn, EidxI, Omat, outE);
}

// Round 11
// 121.581 us; speedup vs baseline: 1.1312x; 1.0576x over previous
//
#include <hip/hip_runtime.h>
#include <math.h>

// Problem constants (from setup_inputs)
constexpr int Lc   = 4096;
constexpr int Bc   = 2;
constexpr int KNB  = 30;    // TOP_K
constexpr int NF   = 167;   // 16 pos + 144 rbf + 7 orient
constexpr int NC   = 128;   // output channels
constexpr int KP   = 200;   // padded K stride (bf16 elems) -> 400B row stride
constexpr int NKT  = 6;     // K-tiles of 32 (192 >= 167)
constexpr int CAP  = 512;   // fallback candidate capacity

typedef __attribute__((ext_vector_type(8))) short bf16x8;
typedef __attribute__((ext_vector_type(4))) float f32x4;

struct V3 { float x, y, z; };

__device__ __forceinline__ float sgnf(float v) {
    return (v > 0.f) ? 1.f : ((v < 0.f) ? -1.f : 0.f);
}
__device__ __forceinline__ unsigned long long umin64(unsigned long long a, unsigned long long b) {
    return a < b ? a : b;
}
__device__ __forceinline__ void splitbf(float v, unsigned short& h, unsigned short& l) {
    unsigned u = __float_as_uint(v);
    h = (unsigned short)(u >> 16);
    float fh = __uint_as_float((unsigned)h << 16);
    l = (unsigned short)(__float_as_uint(v - fh) >> 16);
}
__device__ __forceinline__ unsigned short bf16rne(float v) {
    unsigned u = __float_as_uint(v);
    return (unsigned short)((u + 0x7FFFu + ((u >> 16) & 1u)) >> 16);
}

// ---------------------------------------------------------------------------
// Kernel 0: pack edge_W (167x128 f32) into MFMA-fragment-ordered bf16 hi/lo.
// ---------------------------------------------------------------------------
__global__ void pack_kernel(const float* __restrict__ W,
                            unsigned short* __restrict__ Wh,
                            unsigned short* __restrict__ Wl) {
    int t = blockIdx.x * blockDim.x + threadIdx.x;
    if (t >= NKT * 8 * 64) return;
    int lane = t & 63, nt = (t >> 6) & 7, kt = t >> 9;
    int n = nt * 16 + (lane & 15);
    int kbase = kt * 32 + (lane >> 4) * 8;
    __align__(16) unsigned short h[8], l[8];
#pragma unroll
    for (int j = 0; j < 8; ++j) {
        int k = kbase + j;
        float v = (k < NF) ? W[(size_t)k * NC + n] : 0.f;
        splitbf(v, h[j], l[j]);
    }
    size_t o = (size_t)t * 8;
    *(bf16x8*)(Wh + o) = *(const bf16x8*)h;
    *(bf16x8*)(Wl + o) = *(const bf16x8*)l;
}

// ---------------------------------------------------------------------------
// Kernel 1 (v6): masked distance + top-30 in squared-distance space.
// (Dn no longer produced: edge recomputes block-0 RBF distance directly.)
// ---------------------------------------------------------------------------
__global__ __launch_bounds__(256) void topk_kernel(
    const float* __restrict__ Ca, const float* __restrict__ mask,
    float* __restrict__ EidxF, int* __restrict__ EidxI) {
    const int row = blockIdx.x;                 // b*L + i
    const int b = row >> 12, i = row & (Lc - 1);
    const float* CaB = Ca + (size_t)b * Lc * 3;
    const float* mB  = mask + (size_t)b * Lc;
    const float xi = CaB[i * 3 + 0], yi = CaB[i * 3 + 1], zi = CaB[i * 3 + 2];
    const float mi = mB[i];

    __shared__ unsigned long long cand[CAP];         // 4 KB
    __shared__ float redf[4];
    __shared__ int redi[2][4];
    __shared__ int candN;

    const int t = threadIdx.x, lane = t & 63, wid = t >> 6;
    if (t == 0) candN = 0;

    float ss[16], m2a[16];
    float lmax = -1e30f;
#pragma unroll
    for (int k = 0; k < 16; ++k) {
        int j = t + k * 256;
        float dx = CaB[j * 3 + 0] - xi;
        float dy = CaB[j * 3 + 1] - yi;
        float dz = CaB[j * 3 + 2] - zi;
        float s = dx * dx + dy * dy + dz * dz;
        float m2 = mi * mB[j];
        float v = m2 * s;
        ss[k] = v; m2a[k] = m2;
        lmax = fmaxf(lmax, v);
    }
    for (int off = 32; off; off >>= 1) lmax = fmaxf(lmax, __shfl_xor(lmax, off));
    if (lane == 0) redf[wid] = lmax;
    __syncthreads();
    const float ssmax = fmaxf(fmaxf(redf[0], redf[1]), fmaxf(redf[2], redf[3]));

#pragma unroll
    for (int k = 0; k < 16; ++k) ss[k] = ss[k] + (1.f - m2a[k]) * ssmax;

    float T = ssmax * 0.037772f;   // (30/4096)^(2/3)
    int c = 0;
    for (int iter = 0; iter < 32; ++iter) {
        int lc = 0;
#pragma unroll
        for (int k = 0; k < 16; ++k) lc += (ss[k] <= T) ? 1 : 0;
        for (int off = 32; off; off >>= 1) lc += __shfl_xor(lc, off);
        if (lane == 0) redi[iter & 1][wid] = lc;
        __syncthreads();
        c = redi[iter & 1][0] + redi[iter & 1][1] + redi[iter & 1][2] + redi[iter & 1][3];
        if (c >= KNB && c <= 64) break;
        if (iter >= 12 && c >= KNB && c <= CAP) break;
        if (c < KNB) {
            if (c == 0) T *= 2.89f;
            else {
                float f = cbrtf((float)(KNB + 15) / (float)c);
                T *= fminf(2.89f, 1.1025f * f * f);
            }
        } else {
            float f = cbrtf(45.f / (float)c);
            T *= fmaxf(0.3025f, 1.1025f * f * f);
        }
    }

#pragma unroll
    for (int k = 0; k < 16; ++k) {
        if (ss[k] <= T) {
            int idx = atomicAdd(&candN, 1);
            if (idx < CAP)
                cand[idx] = ((unsigned long long)__float_as_uint(ss[k]) << 32) |
                            (unsigned)(t + k * 256);
        }
    }
    __syncthreads();

    if (wid == 0) {
        int C = candN; if (C > CAP) C = CAP;
        if (C <= 64) {
            unsigned long long key = (lane < C) ? cand[lane] : ~0ULL;
#pragma unroll
            for (int size = 2; size <= 64; size <<= 1) {
#pragma unroll
                for (int stride = size >> 1; stride; stride >>= 1) {
                    unsigned long long other = __shfl_xor(key, stride);
                    bool dirUp = ((lane & size) == 0);
                    bool takeMin = ((lane & stride) == 0) ? dirUp : !dirUp;
                    bool less = other < key;
                    unsigned long long mn = less ? other : key;
                    unsigned long long mx = less ? key : other;
                    key = takeMin ? mn : mx;
                }
            }
            if (lane < KNB) {
                int jw = (int)(key & 0xFFFFFFFFULL);
                EidxF[(size_t)row * KNB + lane] = (float)jw;
                EidxI[(size_t)row * KNB + lane] = jw;
            }
        } else {
            unsigned long long r[CAP / 64];
#pragma unroll
            for (int q = 0; q < CAP / 64; ++q) {
                int idx = lane + q * 64;
                r[q] = (idx < C) ? cand[idx] : ~0ULL;
            }
            for (int p = 0; p < KNB; ++p) {
                unsigned long long mn = r[0];
#pragma unroll
                for (int q = 1; q < CAP / 64; ++q) mn = umin64(mn, r[q]);
                for (int off = 32; off; off >>= 1) mn = umin64(mn, __shfl_xor(mn, off));
                if (lane == 0) {
                    int jw = (int)(mn & 0xFFFFFFFFULL);
                    EidxF[(size_t)row * KNB + p] = (float)jw;
                    EidxI[(size_t)row * KNB + p] = jw;
                }
#pragma unroll
                for (int q = 0; q < CAP / 64; ++q) if (r[q] == mn) r[q] = ~0ULL;
            }
        }
    }
}

// ---------------------------------------------------------------------------
// Kernel 2: per-node orientation frame O (unchanged).
// ---------------------------------------------------------------------------
__device__ __forceinline__ V3 unit_seg(float dx, float dy, float dz) {
    float n = sqrtf(dx * dx + dy * dy + dz * dz);
    float m = (n > 3.6f && n < 4.0f) ? 1.f : 0.f;
    float nn = fmaxf(m * n, 1e-12f);
    V3 r; r.x = dx * m / nn; r.y = dy * m / nn; r.z = dz * m / nn;
    return r;
}

__global__ void orient_kernel(const float* __restrict__ Ca, float* __restrict__ O) {
    int idx = blockIdx.x * blockDim.x + threadIdx.x;
    if (idx >= Bc * Lc) return;
    int b = idx >> 12, l = idx & (Lc - 1);
    float* o = O + (size_t)idx * 9;
    if (l < 1 || l >= Lc - 2) {
#pragma unroll
        for (int q = 0; q < 9; ++q) o[q] = 0.f;
        return;
    }
    const float* C = Ca + ((size_t)b * Lc + (l - 1)) * 3;
    float ax = C[0], ay = C[1], az = C[2];
    float bx = C[3], by = C[4], bz = C[5];
    float cx = C[6], cy = C[7], cz = C[8];
    V3 u2 = unit_seg(bx - ax, by - ay, bz - az);
    V3 u1 = unit_seg(cx - bx, cy - by, cz - bz);
    float nx = u2.y * u1.z - u2.z * u1.y;
    float ny = u2.z * u1.x - u2.x * u1.z;
    float nz = u2.x * u1.y - u2.y * u1.x;
    float nn = fmaxf(sqrtf(nx * nx + ny * ny + nz * nz), 1e-12f);
    nx /= nn; ny /= nn; nz /= nn;
    float ox = u2.x - u1.x, oy = u2.y - u1.y, oz = u2.z - u1.z;
    float on = fmaxf(sqrtf(ox * ox + oy * oy + oz * oz), 1e-12f);
    ox /= on; oy /= on; oz /= on;
    float rx = oy * nz - oz * ny;
    float ry = oz * nx - ox * nz;
    float rz = ox * ny - oy * nx;
    o[0] = ox; o[1] = oy; o[2] = oz;
    o[3] = nx; o[4] = ny; o[5] = nz;
    o[6] = rx; o[7] = ry; o[8] = rz;
}

// ---------------------------------------------------------------------------
// Kernel 3 (v5): features with UNIFORM-BRANCH task layout + MFMA + in-reg LN.
// Round 1: all 256 threads run one RBF body (tasks 0..255 of 270).
// Round 2: wave0 = RBF tail (14), wave1 = pos (30), wave2 = orient (30).
// g==1 RBF computed like any pair (shift 1,1) == sqrt(ss+1e-6) == D_neighbors.
// ---------------------------------------------------------------------------
__global__ __launch_bounds__(256) void edge_kernel(
    const float* __restrict__ Ca, const int* __restrict__ ridx,
    const int* __restrict__ clab, const float* __restrict__ pos_W,
    const float* __restrict__ pos_b,
    const unsigned short* __restrict__ Wh, const unsigned short* __restrict__ Wl,
    const float* __restrict__ ln_g, const float* __restrict__ ln_b,
    const int* __restrict__ EidxI, const float* __restrict__ Omat,
    float* __restrict__ outE) {
    const int row = blockIdx.x;                 // b*L + i
    const int b = row >> 12, i = row & (Lc - 1);
    const int tid = threadIdx.x, lane = tid & 63, w = tid >> 6;

    __shared__ __align__(16) unsigned short Fh[32][KP];   // 12.5 KB
    __shared__ float Ssum[32][4];
    __shared__ float Ssq[32][4];
    __shared__ float2 Mstat[32];
    __shared__ int Ej[32];

    const float* CaB = Ca + (size_t)b * Lc * 3;

    // --- targeted zero-fill: padding cols 167..199 all rows; rows 30,31 ---
    for (int q = tid; q < 32 * 33; q += 256) {
        int r = q / 33, c = 167 + q % 33;
        Fh[r][c] = 0;
    }
    for (int q = tid; q < 2 * 167; q += 256) {
        int r = 30 + q / 167, c = q % 167;
        Fh[r][c] = 0;
    }
    if (tid < KNB) Ej[tid] = EidxI[(size_t)row * KNB + tid];
    __syncthreads();

    auto putF2 = [&](int e, int k, float va, float vb) {   // k even
        unsigned pv = (unsigned)bf16rne(va) | ((unsigned)bf16rne(vb) << 16);
        *(unsigned*)&Fh[e][k] = pv;
    };
    auto loadC = [&](int n) {
        V3 r;
        if (n >= 0 && n < Lc) { r.x = CaB[n*3]; r.y = CaB[n*3+1]; r.z = CaB[n*3+2]; }
        else { r.x = 0.f; r.y = 0.f; r.z = 0.f; }
        return r;
    };

    // RBF body: task r in [0,270): e = r%30, g = r/30+1; shifts packed in bits.
    auto rbf_task = [&](int r) {
        int e = r % 30, g = r / 30 + 1;
        int j = Ej[e];
        int pa = (int)((0xA5084u >> (2 * g)) & 3u);
        int pb = (int)((0x48984u >> (2 * g)) & 3u);
        V3 A = loadC(i - 1 + pa);
        V3 B = loadC(j - 1 + pb);
        float dx = A.x - B.x, dy = A.y - B.y, dz = A.z - B.z;
        float D = sqrtf(dx * dx + dy * dy + dz * dz + 1e-6f);
        int k0 = 16 * g;
#pragma unroll
        for (int m = 0; m < 16; m += 2) {
            float z0 = (D - (2.f + (20.f / 15.f) * (float)m)) * (1.f / 1.25f);
            float z1 = (D - (2.f + (20.f / 15.f) * (float)(m + 1))) * (1.f / 1.25f);
            putF2(e, k0 + m, __expf(-z0 * z0), __expf(-z1 * z1));
        }
    };

    // Round 1: fully uniform — every thread one RBF task.
    rbf_task(tid);

    // Round 2: one branch body per wave.
    if (w == 0) {
        if (lane < 14) rbf_task(256 + lane);
    } else if (w == 1) {
        if (lane < KNB) {
            int e = lane, j = Ej[e];
            int off = ridx[(size_t)b * Lc + i] - ridx[(size_t)b * Lc + j];
            int ec = (clab[(size_t)b * Lc + i] == clab[(size_t)b * Lc + j]) ? 1 : 0;
            int d = ec ? min(max(off + 32, 0), 64) : 65;
#pragma unroll
            for (int cc = 0; cc < 16; cc += 2)
                putF2(e, cc, pos_W[d * 16 + cc] + pos_b[cc],
                             pos_W[d * 16 + cc + 1] + pos_b[cc + 1]);
        }
    } else if (w == 2) {
        if (lane < KNB) {
            int e = lane, j = Ej[e];
            const float* Om = Omat + (size_t)row * 9;
            const float* On = Omat + ((size_t)b * Lc + j) * 9;
            V3 Ai = loadC(i), Bj = loadC(j);
            float dvx = Bj.x - Ai.x, dvy = Bj.y - Ai.y, dvz = Bj.z - Ai.z;
            float u0 = Om[0] * dvx + Om[1] * dvy + Om[2] * dvz;
            float u1 = Om[3] * dvx + Om[4] * dvy + Om[5] * dvz;
            float u2 = Om[6] * dvx + Om[7] * dvy + Om[8] * dvz;
            float un = fmaxf(sqrtf(u0 * u0 + u1 * u1 + u2 * u2), 1e-12f);
            float R[3][3];
#pragma unroll
            for (int a = 0; a < 3; ++a)
#pragma unroll
                for (int m = 0; m < 3; ++m)
                    R[a][m] = Om[0 * 3 + a] * On[0 * 3 + m] +
                              Om[1 * 3 + a] * On[1 * 3 + m] +
                              Om[2 * 3 + a] * On[2 * 3 + m];
            float Rxx = R[0][0], Ryy = R[1][1], Rzz = R[2][2];
            float m0 = 0.5f * sqrtf(fabsf(1.f + Rxx - Ryy - Rzz));
            float m1 = 0.5f * sqrtf(fabsf(1.f - Rxx + Ryy - Rzz));
            float m2 = 0.5f * sqrtf(fabsf(1.f - Rxx - Ryy + Rzz));
            float qx = sgnf(R[2][1] - R[1][2]) * m0;
            float qy = sgnf(R[0][2] - R[2][0]) * m1;
            float qz = sgnf(R[1][0] - R[0][1]) * m2;
            float qw = sqrtf(fmaxf(0.f, 1.f + Rxx + Ryy + Rzz)) * 0.5f;
            float qn = fmaxf(sqrtf(qx * qx + qy * qy + qz * qz + qw * qw), 1e-12f);
            putF2(e, 160, u0 / un, u1 / un);
            putF2(e, 162, u2 / un, qx / qn);
            putF2(e, 164, qy / qn, qz / qn);
            putF2(e, 166, qw / qn, 0.f);      // col 167 is zero padding
        }
    }
    __syncthreads();

    // --- MFMA phase: wave w owns N columns [w*32, w*32+32) ---
    const int arow = lane & 15, agrp = lane >> 4;
    const int ng0 = w * 2;
    f32x4 acc[2][2];
#pragma unroll
    for (int m = 0; m < 2; ++m)
#pragma unroll
        for (int n = 0; n < 2; ++n) acc[m][n] = (f32x4){0.f, 0.f, 0.f, 0.f};

    const bf16x8* WhF = (const bf16x8*)Wh;
    const bf16x8* WlF = (const bf16x8*)Wl;

#pragma unroll
    for (int kt = 0; kt < NKT; ++kt) {
        const int kof = kt * 32 + agrp * 8;
        bf16x8 a0 = *(const bf16x8*)&Fh[arow][kof];
        bf16x8 a1 = *(const bf16x8*)&Fh[16 + arow][kof];
        bf16x8 b0h = WhF[(kt * 8 + ng0) * 64 + lane];
        bf16x8 b1h = WhF[(kt * 8 + ng0 + 1) * 64 + lane];
        bf16x8 b0l = WlF[(kt * 8 + ng0) * 64 + lane];
        bf16x8 b1l = WlF[(kt * 8 + ng0 + 1) * 64 + lane];

        acc[0][0] = __builtin_amdgcn_mfma_f32_16x16x32_bf16(a0, b0h, acc[0][0], 0, 0, 0);
        acc[0][0] = __builtin_amdgcn_mfma_f32_16x16x32_bf16(a0, b0l, acc[0][0], 0, 0, 0);
        acc[0][1] = __builtin_amdgcn_mfma_f32_16x16x32_bf16(a0, b1h, acc[0][1], 0, 0, 0);
        acc[0][1] = __builtin_amdgcn_mfma_f32_16x16x32_bf16(a0, b1l, acc[0][1], 0, 0, 0);
        acc[1][0] = __builtin_amdgcn_mfma_f32_16x16x32_bf16(a1, b0h, acc[1][0], 0, 0, 0);
        acc[1][0] = __builtin_amdgcn_mfma_f32_16x16x32_bf16(a1, b0l, acc[1][0], 0, 0, 0);
        acc[1][1] = __builtin_amdgcn_mfma_f32_16x16x32_bf16(a1, b1h, acc[1][1], 0, 0, 0);
        acc[1][1] = __builtin_amdgcn_mfma_f32_16x16x32_bf16(a1, b1l, acc[1][1], 0, 0, 0);
    }

    // --- LN stats from accumulators ---
    float ps[2][4], pq[2][4];
#pragma unroll
    for (int m = 0; m < 2; ++m)
#pragma unroll
        for (int r = 0; r < 4; ++r) {
            float v0 = acc[m][0][r], v1 = acc[m][1][r];
            ps[m][r] = v0 + v1;
            pq[m][r] = v0 * v0 + v1 * v1;
        }
#pragma unroll
    for (int off = 1; off < 16; off <<= 1) {
#pragma unroll
        for (int m = 0; m < 2; ++m)
#pragma unroll
            for (int r = 0; r < 4; ++r) {
                ps[m][r] += __shfl_xor(ps[m][r], off);
                pq[m][r] += __shfl_xor(pq[m][r], off);
            }
    }
    if (arow == 0) {
#pragma unroll
        for (int m = 0; m < 2; ++m)
#pragma unroll
            for (int r = 0; r < 4; ++r) {
                int me = m * 16 + agrp * 4 + r;
                Ssum[me][w] = ps[m][r];
                Ssq[me][w] = pq[m][r];
            }
    }
    __syncthreads();
    if (tid < 32) {
        float s = Ssum[tid][0] + Ssum[tid][1] + Ssum[tid][2] + Ssum[tid][3];
        float q = Ssq[tid][0] + Ssq[tid][1] + Ssq[tid][2] + Ssq[tid][3];
        float mean = s * (1.f / 128.f);
        float var = q * (1.f / 128.f) - mean * mean;
        Mstat[tid] = make_float2(mean, 1.f / sqrtf(var + 1e-5f));
    }
    __syncthreads();

    float gg[2], bb[2];
#pragma unroll
    for (int n = 0; n < 2; ++n) {
        int ce = (ng0 + n) * 16 + arow;
        gg[n] = ln_g[ce];
        bb[n] = ln_b[ce];
    }
#pragma unroll
    for (int m = 0; m < 2; ++m)
#pragma unroll
        for (int r = 0; r < 4; ++r) {
            int me = m * 16 + agrp * 4 + r;
            if (me >= KNB) continue;
            float2 st = Mstat[me];
            size_t base = ((size_t)row * KNB + me) * NC;
#pragma unroll
            for (int n = 0; n < 2; ++n) {
                int ce = (ng0 + n) * 16 + arow;
                outE[base + ce] = (acc[m][n][r] - st.x) * st.y * gg[n] + bb[n];
            }
        }
}

// ---------------------------------------------------------------------------
extern "C" void kernel_launch(void* const* d_in, const int* in_sizes, int n_in,
                              void* d_out, int out_size, void* d_ws, size_t ws_size,
                              hipStream_t stream) {
    const float* Ca     = (const float*)d_in[0];
    const float* mask   = (const float*)d_in[1];
    const int*   ridx   = (const int*)d_in[2];
    const int*   clab   = (const int*)d_in[3];
    const float* pos_W  = (const float*)d_in[4];
    const float* pos_b  = (const float*)d_in[5];
    const float* edge_W = (const float*)d_in[6];
    const float* ln_g   = (const float*)d_in[7];
    const float* ln_b   = (const float*)d_in[8];

    float* outE  = (float*)d_out;
    float* EidxF = outE + (size_t)Bc * Lc * KNB * NC;   // output 1 (as float values)

    float* Omat  = (float*)d_ws;                           // B*L*9 f32
    int*   EidxI = (int*)(Omat + (size_t)Bc * Lc * 9);     // B*L*30 i32
    unsigned short* Wh = (unsigned short*)(EidxI + (size_t)Bc * Lc * KNB);
    unsigned short* Wl = Wh + (size_t)NKT * 8 * 64 * 8;    // 24576 each

    const int rows = Bc * Lc;
    pack_kernel<<<12, 256, 0, stream>>>(edge_W, Wh, Wl);
    topk_kernel<<<rows, 256, 0, stream>>>(Ca, mask, EidxF, EidxI);
    orient_kernel<<<(rows + 255) / 256, 256, 0, stream>>>(Ca, Omat);
    edge_kernel<<<rows, 256, 0, stream>>>(Ca, ridx, clab, pos_W, pos_b, Wh, Wl,
                                          ln_g, ln_b, EidxI, Omat, outE);
}

// Round 12
// 116.165 us; speedup vs baseline: 1.1839x; 1.0466x over previous
//
#include <hip/hip_runtime.h>
#include <math.h>

// Problem constants (from setup_inputs)
constexpr int Lc   = 4096;
constexpr int Bc   = 2;
constexpr int KNB  = 30;    // TOP_K
constexpr int NF   = 167;   // 16 pos + 144 rbf + 7 orient
constexpr int NC   = 128;   // output channels
constexpr int KP   = 200;   // padded K stride (bf16 elems) -> 400B row stride
constexpr int NKT  = 6;     // K-tiles of 32 (192 >= 167)
constexpr int CAP  = 512;   // fallback candidate capacity

typedef __attribute__((ext_vector_type(8))) short bf16x8;
typedef __attribute__((ext_vector_type(4))) float f32x4;

struct V3 { float x, y, z; };

__device__ __forceinline__ float sgnf(float v) {
    return (v > 0.f) ? 1.f : ((v < 0.f) ? -1.f : 0.f);
}
__device__ __forceinline__ unsigned long long umin64(unsigned long long a, unsigned long long b) {
    return a < b ? a : b;
}
__device__ __forceinline__ void splitbf(float v, unsigned short& h, unsigned short& l) {
    unsigned u = __float_as_uint(v);
    h = (unsigned short)(u >> 16);
    float fh = __uint_as_float((unsigned)h << 16);
    l = (unsigned short)(__float_as_uint(v - fh) >> 16);
}
// packed f32x2 -> bf16x2 (RTNE), single instruction; lo = a, hi = b
__device__ __forceinline__ unsigned cvtpk(float a, float b) {
    unsigned r;
    asm("v_cvt_pk_bf16_f32 %0, %1, %2" : "=v"(r) : "v"(a), "v"(b));
    return r;
}

// ---------------------------------------------------------------------------
// Kernel 0 (merged): blocks 0..31 orient, blocks 32..43 pack.
// ---------------------------------------------------------------------------
__device__ __forceinline__ V3 unit_seg(float dx, float dy, float dz) {
    float n = sqrtf(dx * dx + dy * dy + dz * dz);
    float m = (n > 3.6f && n < 4.0f) ? 1.f : 0.f;
    float nn = fmaxf(m * n, 1e-12f);
    V3 r; r.x = dx * m / nn; r.y = dy * m / nn; r.z = dz * m / nn;
    return r;
}

__global__ void prep_kernel(const float* __restrict__ Ca, float* __restrict__ O,
                            const float* __restrict__ W,
                            unsigned short* __restrict__ Wh,
                            unsigned short* __restrict__ Wl) {
    if (blockIdx.x < 32) {
        int idx = blockIdx.x * 256 + threadIdx.x;
        if (idx >= Bc * Lc) return;
        int b = idx >> 12, l = idx & (Lc - 1);
        float* o = O + (size_t)idx * 9;
        if (l < 1 || l >= Lc - 2) {
#pragma unroll
            for (int q = 0; q < 9; ++q) o[q] = 0.f;
            return;
        }
        const float* C = Ca + ((size_t)b * Lc + (l - 1)) * 3;
        float ax = C[0], ay = C[1], az = C[2];
        float bx = C[3], by = C[4], bz = C[5];
        float cx = C[6], cy = C[7], cz = C[8];
        V3 u2 = unit_seg(bx - ax, by - ay, bz - az);
        V3 u1 = unit_seg(cx - bx, cy - by, cz - bz);
        float nx = u2.y * u1.z - u2.z * u1.y;
        float ny = u2.z * u1.x - u2.x * u1.z;
        float nz = u2.x * u1.y - u2.y * u1.x;
        float nn = fmaxf(sqrtf(nx * nx + ny * ny + nz * nz), 1e-12f);
        nx /= nn; ny /= nn; nz /= nn;
        float ox = u2.x - u1.x, oy = u2.y - u1.y, oz = u2.z - u1.z;
        float on = fmaxf(sqrtf(ox * ox + oy * oy + oz * oz), 1e-12f);
        ox /= on; oy /= on; oz /= on;
        float rx = oy * nz - oz * ny;
        float ry = oz * nx - ox * nz;
        float rz = ox * ny - oy * nx;
        o[0] = ox; o[1] = oy; o[2] = oz;
        o[3] = nx; o[4] = ny; o[5] = nz;
        o[6] = rx; o[7] = ry; o[8] = rz;
    } else {
        int t = (blockIdx.x - 32) * 256 + threadIdx.x;
        if (t >= NKT * 8 * 64) return;
        int lane = t & 63, nt = (t >> 6) & 7, kt = t >> 9;
        int n = nt * 16 + (lane & 15);
        int kbase = kt * 32 + (lane >> 4) * 8;
        __align__(16) unsigned short h[8], l[8];
#pragma unroll
        for (int j = 0; j < 8; ++j) {
            int k = kbase + j;
            float v = (k < NF) ? W[(size_t)k * NC + n] : 0.f;
            splitbf(v, h[j], l[j]);
        }
        size_t o = (size_t)t * 8;
        *(bf16x8*)(Wh + o) = *(const bf16x8*)h;
        *(bf16x8*)(Wl + o) = *(const bf16x8*)l;
    }
}

// ---------------------------------------------------------------------------
// Kernel 1 (v6): masked distance + top-30 in squared-distance space
// (unchanged from R11).
// ---------------------------------------------------------------------------
__global__ __launch_bounds__(256) void topk_kernel(
    const float* __restrict__ Ca, const float* __restrict__ mask,
    float* __restrict__ EidxF, int* __restrict__ EidxI) {
    const int row = blockIdx.x;                 // b*L + i
    const int b = row >> 12, i = row & (Lc - 1);
    const float* CaB = Ca + (size_t)b * Lc * 3;
    const float* mB  = mask + (size_t)b * Lc;
    const float xi = CaB[i * 3 + 0], yi = CaB[i * 3 + 1], zi = CaB[i * 3 + 2];
    const float mi = mB[i];

    __shared__ unsigned long long cand[CAP];         // 4 KB
    __shared__ float redf[4];
    __shared__ int redi[2][4];
    __shared__ int candN;

    const int t = threadIdx.x, lane = t & 63, wid = t >> 6;
    if (t == 0) candN = 0;

    float ss[16], m2a[16];
    float lmax = -1e30f;
#pragma unroll
    for (int k = 0; k < 16; ++k) {
        int j = t + k * 256;
        float dx = CaB[j * 3 + 0] - xi;
        float dy = CaB[j * 3 + 1] - yi;
        float dz = CaB[j * 3 + 2] - zi;
        float s = dx * dx + dy * dy + dz * dz;
        float m2 = mi * mB[j];
        float v = m2 * s;
        ss[k] = v; m2a[k] = m2;
        lmax = fmaxf(lmax, v);
    }
    for (int off = 32; off; off >>= 1) lmax = fmaxf(lmax, __shfl_xor(lmax, off));
    if (lane == 0) redf[wid] = lmax;
    __syncthreads();
    const float ssmax = fmaxf(fmaxf(redf[0], redf[1]), fmaxf(redf[2], redf[3]));

#pragma unroll
    for (int k = 0; k < 16; ++k) ss[k] = ss[k] + (1.f - m2a[k]) * ssmax;

    float T = ssmax * 0.037772f;   // (30/4096)^(2/3)
    int c = 0;
    for (int iter = 0; iter < 32; ++iter) {
        int lc = 0;
#pragma unroll
        for (int k = 0; k < 16; ++k) lc += (ss[k] <= T) ? 1 : 0;
        for (int off = 32; off; off >>= 1) lc += __shfl_xor(lc, off);
        if (lane == 0) redi[iter & 1][wid] = lc;
        __syncthreads();
        c = redi[iter & 1][0] + redi[iter & 1][1] + redi[iter & 1][2] + redi[iter & 1][3];
        if (c >= KNB && c <= 64) break;
        if (iter >= 12 && c >= KNB && c <= CAP) break;
        if (c < KNB) {
            if (c == 0) T *= 2.89f;
            else {
                float f = cbrtf((float)(KNB + 15) / (float)c);
                T *= fminf(2.89f, 1.1025f * f * f);
            }
        } else {
            float f = cbrtf(45.f / (float)c);
            T *= fmaxf(0.3025f, 1.1025f * f * f);
        }
    }

#pragma unroll
    for (int k = 0; k < 16; ++k) {
        if (ss[k] <= T) {
            int idx = atomicAdd(&candN, 1);
            if (idx < CAP)
                cand[idx] = ((unsigned long long)__float_as_uint(ss[k]) << 32) |
                            (unsigned)(t + k * 256);
        }
    }
    __syncthreads();

    if (wid == 0) {
        int C = candN; if (C > CAP) C = CAP;
        if (C <= 64) {
            unsigned long long key = (lane < C) ? cand[lane] : ~0ULL;
#pragma unroll
            for (int size = 2; size <= 64; size <<= 1) {
#pragma unroll
                for (int stride = size >> 1; stride; stride >>= 1) {
                    unsigned long long other = __shfl_xor(key, stride);
                    bool dirUp = ((lane & size) == 0);
                    bool takeMin = ((lane & stride) == 0) ? dirUp : !dirUp;
                    bool less = other < key;
                    unsigned long long mn = less ? other : key;
                    unsigned long long mx = less ? key : other;
                    key = takeMin ? mn : mx;
                }
            }
            if (lane < KNB) {
                int jw = (int)(key & 0xFFFFFFFFULL);
                EidxF[(size_t)row * KNB + lane] = (float)jw;
                EidxI[(size_t)row * KNB + lane] = jw;
            }
        } else {
            unsigned long long r[CAP / 64];
#pragma unroll
            for (int q = 0; q < CAP / 64; ++q) {
                int idx = lane + q * 64;
                r[q] = (idx < C) ? cand[idx] : ~0ULL;
            }
            for (int p = 0; p < KNB; ++p) {
                unsigned long long mn = r[0];
#pragma unroll
                for (int q = 1; q < CAP / 64; ++q) mn = umin64(mn, r[q]);
                for (int off = 32; off; off >>= 1) mn = umin64(mn, __shfl_xor(mn, off));
                if (lane == 0) {
                    int jw = (int)(mn & 0xFFFFFFFFULL);
                    EidxF[(size_t)row * KNB + p] = (float)jw;
                    EidxI[(size_t)row * KNB + p] = jw;
                }
#pragma unroll
                for (int q = 0; q < CAP / 64; ++q) if (r[q] == mn) r[q] = ~0ULL;
            }
        }
    }
}

// ---------------------------------------------------------------------------
// Kernel 2 (v6): features (uniform-branch layout, cvt_pk packing) + MFMA +
// in-register LayerNorm.
// ---------------------------------------------------------------------------
__global__ __launch_bounds__(256) void edge_kernel(
    const float* __restrict__ Ca, const int* __restrict__ ridx,
    const int* __restrict__ clab, const float* __restrict__ pos_W,
    const float* __restrict__ pos_b,
    const unsigned short* __restrict__ Wh, const unsigned short* __restrict__ Wl,
    const float* __restrict__ ln_g, const float* __restrict__ ln_b,
    const int* __restrict__ EidxI, const float* __restrict__ Omat,
    float* __restrict__ outE) {
    const int row = blockIdx.x;                 // b*L + i
    const int b = row >> 12, i = row & (Lc - 1);
    const int tid = threadIdx.x, lane = tid & 63, w = tid >> 6;

    __shared__ __align__(16) unsigned short Fh[32][KP];   // 12.5 KB
    __shared__ float Ssum[32][4];
    __shared__ float Ssq[32][4];
    __shared__ float2 Mstat[32];
    __shared__ int Ej[32];

    const float* CaB = Ca + (size_t)b * Lc * 3;

    // --- targeted zero-fill: padding cols 167..199 all rows; rows 30,31 ---
    for (int q = tid; q < 32 * 33; q += 256) {
        int r = q / 33, c = 167 + q % 33;
        Fh[r][c] = 0;
    }
    for (int q = tid; q < 2 * 167; q += 256) {
        int r = 30 + q / 167, c = q % 167;
        Fh[r][c] = 0;
    }
    if (tid < KNB) Ej[tid] = EidxI[(size_t)row * KNB + tid];
    __syncthreads();

    auto putF2 = [&](int e, int k, float va, float vb) {   // k even
        *(unsigned*)&Fh[e][k] = cvtpk(va, vb);
    };
    auto loadC = [&](int n) {
        V3 r;
        if (n >= 0 && n < Lc) { r.x = CaB[n*3]; r.y = CaB[n*3+1]; r.z = CaB[n*3+2]; }
        else { r.x = 0.f; r.y = 0.f; r.z = 0.f; }
        return r;
    };

    // RBF body: task r in [0,270): e = r%30, g = r/30+1; shifts packed in bits.
    // D pre-scaled by 1/1.25: z_m = D8 - mu8_m, mu8_m = (2 + 20m/15)/1.25.
    auto rbf_task = [&](int r) {
        int e = r % 30, g = r / 30 + 1;
        int j = Ej[e];
        int pa = (int)((0xA5084u >> (2 * g)) & 3u);
        int pb = (int)((0x48984u >> (2 * g)) & 3u);
        V3 A = loadC(i - 1 + pa);
        V3 B = loadC(j - 1 + pb);
        float dx = A.x - B.x, dy = A.y - B.y, dz = A.z - B.z;
        float D8 = sqrtf(dx * dx + dy * dy + dz * dz + 1e-6f) * (1.f / 1.25f);
        int k0 = 16 * g;
#pragma unroll
        for (int m = 0; m < 16; m += 2) {
            float z0 = D8 - (2.f + (20.f / 15.f) * (float)m) * (1.f / 1.25f);
            float z1 = D8 - (2.f + (20.f / 15.f) * (float)(m + 1)) * (1.f / 1.25f);
            putF2(e, k0 + m, __expf(-z0 * z0), __expf(-z1 * z1));
        }
    };

    // Round 1: fully uniform — every thread one RBF task.
    rbf_task(tid);

    // Round 2: one branch body per wave.
    if (w == 0) {
        if (lane < 14) rbf_task(256 + lane);
    } else if (w == 1) {
        if (lane < KNB) {
            int e = lane, j = Ej[e];
            int off = ridx[(size_t)b * Lc + i] - ridx[(size_t)b * Lc + j];
            int ec = (clab[(size_t)b * Lc + i] == clab[(size_t)b * Lc + j]) ? 1 : 0;
            int d = ec ? min(max(off + 32, 0), 64) : 65;
#pragma unroll
            for (int cc = 0; cc < 16; cc += 2)
                putF2(e, cc, pos_W[d * 16 + cc] + pos_b[cc],
                             pos_W[d * 16 + cc + 1] + pos_b[cc + 1]);
        }
    } else if (w == 2) {
        if (lane < KNB) {
            int e = lane, j = Ej[e];
            const float* Om = Omat + (size_t)row * 9;
            const float* On = Omat + ((size_t)b * Lc + j) * 9;
            V3 Ai = loadC(i), Bj = loadC(j);
            float dvx = Bj.x - Ai.x, dvy = Bj.y - Ai.y, dvz = Bj.z - Ai.z;
            float u0 = Om[0] * dvx + Om[1] * dvy + Om[2] * dvz;
            float u1 = Om[3] * dvx + Om[4] * dvy + Om[5] * dvz;
            float u2 = Om[6] * dvx + Om[7] * dvy + Om[8] * dvz;
            float un = fmaxf(sqrtf(u0 * u0 + u1 * u1 + u2 * u2), 1e-12f);
            float R[3][3];
#pragma unroll
            for (int a = 0; a < 3; ++a)
#pragma unroll
                for (int m = 0; m < 3; ++m)
                    R[a][m] = Om[0 * 3 + a] * On[0 * 3 + m] +
                              Om[1 * 3 + a] * On[1 * 3 + m] +
                              Om[2 * 3 + a] * On[2 * 3 + m];
            float Rxx = R[0][0], Ryy = R[1][1], Rzz = R[2][2];
            float m0 = 0.5f * sqrtf(fabsf(1.f + Rxx - Ryy - Rzz));
            float m1 = 0.5f * sqrtf(fabsf(1.f - Rxx + Ryy - Rzz));
            float m2 = 0.5f * sqrtf(fabsf(1.f - Rxx - Ryy + Rzz));
            float qx = sgnf(R[2][1] - R[1][2]) * m0;
            float qy = sgnf(R[0][2] - R[2][0]) * m1;
            float qz = sgnf(R[1][0] - R[0][1]) * m2;
            float qw = sqrtf(fmaxf(0.f, 1.f + Rxx + Ryy + Rzz)) * 0.5f;
            float qn = fmaxf(sqrtf(qx * qx + qy * qy + qz * qz + qw * qw), 1e-12f);
            putF2(e, 160, u0 / un, u1 / un);
            putF2(e, 162, u2 / un, qx / qn);
            putF2(e, 164, qy / qn, qz / qn);
            putF2(e, 166, qw / qn, 0.f);      // col 167 is zero padding
        }
    }
    __syncthreads();

    // --- MFMA phase: wave w owns N columns [w*32, w*32+32) ---
    const int arow = lane & 15, agrp = lane >> 4;
    const int ng0 = w * 2;
    f32x4 acc[2][2];
#pragma unroll
    for (int m = 0; m < 2; ++m)
#pragma unroll
        for (int n = 0; n < 2; ++n) acc[m][n] = (f32x4){0.f, 0.f, 0.f, 0.f};

    const bf16x8* WhF = (const bf16x8*)Wh;
    const bf16x8* WlF = (const bf16x8*)Wl;

#pragma unroll
    for (int kt = 0; kt < NKT; ++kt) {
        const int kof = kt * 32 + agrp * 8;
        bf16x8 a0 = *(const bf16x8*)&Fh[arow][kof];
        bf16x8 a1 = *(const bf16x8*)&Fh[16 + arow][kof];
        bf16x8 b0h = WhF[(kt * 8 + ng0) * 64 + lane];
        bf16x8 b1h = WhF[(kt * 8 + ng0 + 1) * 64 + lane];
        bf16x8 b0l = WlF[(kt * 8 + ng0) * 64 + lane];
        bf16x8 b1l = WlF[(kt * 8 + ng0 + 1) * 64 + lane];

        acc[0][0] = __builtin_amdgcn_mfma_f32_16x16x32_bf16(a0, b0h, acc[0][0], 0, 0, 0);
        acc[0][0] = __builtin_amdgcn_mfma_f32_16x16x32_bf16(a0, b0l, acc[0][0], 0, 0, 0);
        acc[0][1] = __builtin_amdgcn_mfma_f32_16x16x32_bf16(a0, b1h, acc[0][1], 0, 0, 0);
        acc[0][1] = __builtin_amdgcn_mfma_f32_16x16x32_bf16(a0, b1l, acc[0][1], 0, 0, 0);
        acc[1][0] = __builtin_amdgcn_mfma_f32_16x16x32_bf16(a1, b0h, acc[1][0], 0, 0, 0);
        acc[1][0] = __builtin_amdgcn_mfma_f32_16x16x32_bf16(a1, b0l, acc[1][0], 0, 0, 0);
        acc[1][1] = __builtin_amdgcn_mfma_f32_16x16x32_bf16(a1, b1h, acc[1][1], 0, 0, 0);
        acc[1][1] = __builtin_amdgcn_mfma_f32_16x16x32_bf16(a1, b1l, acc[1][1], 0, 0, 0);
    }

    // --- LN stats from accumulators ---
    float ps[2][4], pq[2][4];
#pragma unroll
    for (int m = 0; m < 2; ++m)
#pragma unroll
        for (int r = 0; r < 4; ++r) {
            float v0 = acc[m][0][r], v1 = acc[m][1][r];
            ps[m][r] = v0 + v1;
            pq[m][r] = v0 * v0 + v1 * v1;
        }
#pragma unroll
    for (int off = 1; off < 16; off <<= 1) {
#pragma unroll
        for (int m = 0; m < 2; ++m)
#pragma unroll
            for (int r = 0; r < 4; ++r) {
                ps[m][r] += __shfl_xor(ps[m][r], off);
                pq[m][r] += __shfl_xor(pq[m][r], off);
            }
    }
    if (arow == 0) {
#pragma unroll
        for (int m = 0; m < 2; ++m)
#pragma unroll
            for (int r = 0; r < 4; ++r) {
                int me = m * 16 + agrp * 4 + r;
                Ssum[me][w] = ps[m][r];
                Ssq[me][w] = pq[m][r];
            }
    }
    __syncthreads();
    if (tid < 32) {
        float s = Ssum[tid][0] + Ssum[tid][1] + Ssum[tid][2] + Ssum[tid][3];
        float q = Ssq[tid][0] + Ssq[tid][1] + Ssq[tid][2] + Ssq[tid][3];
        float mean = s * (1.f / 128.f);
        float var = q * (1.f / 128.f) - mean * mean;
        Mstat[tid] = make_float2(mean, 1.f / sqrtf(var + 1e-5f));
    }
    __syncthreads();

    float gg[2], bb[2];
#pragma unroll
    for (int n = 0; n < 2; ++n) {
        int ce = (ng0 + n) * 16 + arow;
        gg[n] = ln_g[ce];
        bb[n] = ln_b[ce];
    }
#pragma unroll
    for (int m = 0; m < 2; ++m)
#pragma unroll
        for (int r = 0; r < 4; ++r) {
            int me = m * 16 + agrp * 4 + r;
            if (me >= KNB) continue;
            float2 st = Mstat[me];
            size_t base = ((size_t)row * KNB + me) * NC;
#pragma unroll
            for (int n = 0; n < 2; ++n) {
                int ce = (ng0 + n) * 16 + arow;
                outE[base + ce] = (acc[m][n][r] - st.x) * st.y * gg[n] + bb[n];
            }
        }
}

// ---------------------------------------------------------------------------
extern "C" void kernel_launch(void* const* d_in, const int* in_sizes, int n_in,
                              void* d_out, int out_size, void* d_ws, size_t ws_size,
                              hipStream_t stream) {
    const float* Ca     = (const float*)d_in[0];
    const float* mask   = (const float*)d_in[1];
    const int*   ridx   = (const int*)d_in[2];
    const int*   clab   = (const int*)d_in[3];
    const float* pos_W  = (const float*)d_in[4];
    const float* pos_b  = (const float*)d_in[5];
    const float* edge_W = (const float*)d_in[6];
    const float* ln_g   = (const float*)d_in[7];
    const float* ln_b   = (const float*)d_in[8];

    float* outE  = (float*)d_out;
    float* EidxF = outE + (size_t)Bc * Lc * KNB * NC;   // output 1 (as float values)

    float* Omat  = (float*)d_ws;                           // B*L*9 f32
    int*   EidxI = (int*)(Omat + (size_t)Bc * Lc * 9);     // B*L*30 i32
    unsigned short* Wh = (unsigned short*)(EidxI + (size_t)Bc * Lc * KNB);
    unsigned short* Wl = Wh + (size_t)NKT * 8 * 64 * 8;    // 24576 each

    const int rows = Bc * Lc;
    prep_kernel<<<44, 256, 0, stream>>>(Ca, Omat, edge_W, Wh, Wl);
    topk_kernel<<<rows, 256, 0, stream>>>(Ca, mask, EidxF, EidxI);
    edge_kernel<<<rows, 256, 0, stream>>>(Ca, ridx, clab, pos_W, pos_b, Wh, Wl,
                                          ln_g, ln_b, EidxI, Omat, outE);
}